// Round 3
// baseline (272.407 us; speedup 1.0000x reference)
//
#include <hip/hip_runtime.h>
#include <hip/hip_bf16.h>

#define NB 32
#define NS 1024
#define ND 768
#define BS_TOT (NB * NS)  // 32768
#define NCT 8             // column tiles per row (one per block now)

// sim scale = 1 / (0.7 * sqrt(768))
#define SCALE 0.05154913f

typedef __attribute__((ext_vector_type(8))) short bf16x8;  // 8 bf16 = 4 VGPRs
typedef __attribute__((ext_vector_type(4))) float f32x4;

__device__ __forceinline__ unsigned short f2bf(float f) {
  __hip_bfloat16 h = __float2bfloat16(f);
  return *reinterpret_cast<unsigned short*>(&h);
}

__device__ __forceinline__ void gload_lds16(const unsigned short* g, short* l) {
  __builtin_amdgcn_global_load_lds(
      (const __attribute__((address_space(1))) unsigned int*)g,
      (__attribute__((address_space(3))) unsigned int*)l,
      16 /*bytes*/, 0 /*offset*/, 0 /*aux*/);
}

// ---------------- Kernel 1: fp32 -> bf16 convert (8 elems/thread) ----------
__global__ void cvt_kernel(const float* __restrict__ in,
                           unsigned short* __restrict__ out) {
  int i = (blockIdx.x * 256 + threadIdx.x) * 8;
  float4 v0 = *reinterpret_cast<const float4*>(in + i);
  float4 v1 = *reinterpret_cast<const float4*>(in + i + 4);
  ushort4 o0, o1;
  o0.x = f2bf(v0.x); o0.y = f2bf(v0.y); o0.z = f2bf(v0.z); o0.w = f2bf(v0.w);
  o1.x = f2bf(v1.x); o1.y = f2bf(v1.y); o1.z = f2bf(v1.z); o1.w = f2bf(v1.w);
  *reinterpret_cast<ushort4*>(out + i) = o0;
  *reinterpret_cast<ushort4*>(out + i + 4) = o1;
}

// ---------------- Kernel 2: per-anchor metadata ----------------
// Handles labels arriving as either int32 or raw int64 (little-endian): if
// int64, every odd 32-bit word of the label buffer is the zero high-word.
__global__ void meta_kernel(const int* __restrict__ lr,
                            float* __restrict__ invN,
                            float* __restrict__ invGS,
                            float* __restrict__ numneg,
                            int* __restrict__ labI,
                            float* __restrict__ out) {
  __shared__ int cnt[16];
  __shared__ int is64;
  int b = blockIdx.x, t = threadIdx.x;
  if (t == 0) is64 = 1;
  if (t < 16) cnt[t] = 0;
  __syncthreads();
  int bad = 0;
  for (int k = t; k < 1024; k += 256) bad |= lr[2 * k + 1];
  if (bad) atomicAnd(&is64, 0);
  __syncthreads();
  const bool i64 = (is64 != 0);
  for (int i = t; i < NS; i += 256) {
    int gi = b * NS + i;
    int lab = (i64 ? lr[2 * gi] : lr[gi]) & 15;
    atomicAdd(&cnt[lab], 1);
  }
  __syncthreads();
  for (int i = t; i < NS; i += 256) {
    int gi = b * NS + i;
    int lab = (i64 ? lr[2 * gi] : lr[gi]) & 15;
    int gs = cnt[lab];
    int nn = NS - gs;
    invN[gi] = nn > 0 ? 1.0f / (float)nn : 0.0f;
    invGS[gi] = 1.0f / (float)gs;
    numneg[gi] = (float)nn;
    labI[gi] = lab;
  }
  if (b == 0 && t == 0) out[0] = 0.0f;  // d_out is poisoned before each launch
}

// ---------------- Kernel 3: fused Gram + SupCon epilogue ----------------
// ONE 128x128 sim tile per block. Grid 2048 = 32 batches x 8 row x 8 col
// tiles, decoded XCD-affine: xcd = bid&7 owns batches [4*xcd, 4*xcd+4) so each
// XCD's staging working set is ~6 MB (vs 48 MB striped) for L2 locality.
// 256 threads = 4 waves (2x2 of 64x64), each 4x4 grid of 16x16x32 bf16 MFMAs.
// Splitting to one tile/block keeps total staging bytes identical (every tile
// stages its own A+B regardless) but gives ~4 resident blocks/CU for latency
// hiding, and shrinks K-loop live ranges so __launch_bounds__(256,4) fits.
__global__ __launch_bounds__(256, 4) void gram_kernel(
    const unsigned short* __restrict__ featB, const int* __restrict__ labI,
    const float* __restrict__ invN, float* __restrict__ negP,
    float* __restrict__ posP, float* __restrict__ nltP) {
  const int bid = blockIdx.x;
  const int xcd = bid & 7;
  const int idx = bid >> 3;            // 0..255
  const int b = xcd * 4 + (idx & 3);   // 4 batches per XCD
  const int t2 = idx >> 2;             // 0..63
  const int rt = t2 & 7;
  const int cj = t2 >> 3;              // 0..7 column tile

  const int tid = threadIdx.x;
  const int lane = tid & 63;
  const int w = tid >> 6;
  const int wr = w >> 1, wc = w & 1;
  const int quad = lane >> 4, l15 = lane & 15;

  __shared__ alignas(16) short As[128 * 32];  // 8 KB, row-major [row][k]
  __shared__ alignas(16) short Bs[128 * 32];  // 8 KB, row-major [col][k]
  __shared__ float redL[2][3][128];           // [wc][neg/pos/nlt][row], 3 KB

  const int rowBase = rt * 128;
  const int colBase = cj * 128;
  const size_t featA = (size_t)(b * NS + rowBase) * ND;
  const size_t featBb = (size_t)(b * NS + colBase) * ND;

  f32x4 acc[4][4];
  const f32x4 zv = {0.0f, 0.0f, 0.0f, 0.0f};
#pragma unroll
  for (int rs = 0; rs < 4; ++rs)
#pragma unroll
    for (int csb = 0; csb < 4; ++csb) acc[rs][csb] = zv;

  for (int k0 = 0; k0 < ND; k0 += 32) {
    __syncthreads();  // previous iteration's ds_reads done before restage
#pragma unroll
    for (int rnd = 0; rnd < 2; ++rnd) {
      int s = rnd * 256 + tid;
      int row = s >> 2, ch = s & 3;
      gload_lds16(featB + featA + (size_t)row * ND + k0 + ch * 8, &As[s * 8]);
    }
#pragma unroll
    for (int rnd = 0; rnd < 2; ++rnd) {
      int s = rnd * 256 + tid;
      int row = s >> 2, ch = s & 3;
      gload_lds16(featB + featBb + (size_t)row * ND + k0 + ch * 8, &Bs[s * 8]);
    }
    __syncthreads();  // vmcnt drain: staging visible

    bf16x8 av[4], bv[4];
#pragma unroll
    for (int rs = 0; rs < 4; ++rs)
      av[rs] = *reinterpret_cast<const bf16x8*>(
          &As[(wr * 64 + rs * 16 + l15) * 32 + quad * 8]);
#pragma unroll
    for (int csb = 0; csb < 4; ++csb)
      bv[csb] = *reinterpret_cast<const bf16x8*>(
          &Bs[(wc * 64 + csb * 16 + l15) * 32 + quad * 8]);
#pragma unroll
    for (int rs = 0; rs < 4; ++rs)
#pragma unroll
      for (int csb = 0; csb < 4; ++csb)
        acc[rs][csb] = __builtin_amdgcn_mfma_f32_16x16x32_bf16(
            av[rs], bv[csb], acc[rs][csb], 0, 0, 0);
  }

  // ---- Epilogue (once per block). Column labels for this wave's 64 cols.
  int labc[4];
#pragma unroll
  for (int csb = 0; csb < 4; ++csb)
    labc[csb] = labI[b * NS + colBase + wc * 64 + csb * 16 + l15];

  // rs-by-rs to cap register pressure (acc still live while reducing).
#pragma unroll
  for (int rs = 0; rs < 4; ++rs) {
    int labr[4];
    float eN[4];
    const int ibase = b * NS + rowBase + wr * 64 + rs * 16 + quad * 4;
#pragma unroll
    for (int r = 0; r < 4; ++r) {
      labr[r] = labI[ibase + r];
      eN[r] = invN[ibase + r] * SCALE;
    }
    float neg[4] = {0, 0, 0, 0}, pos[4] = {0, 0, 0, 0}, nlt[4] = {0, 0, 0, 0};
#pragma unroll
    for (int csb = 0; csb < 4; ++csb) {
      int jl = colBase + wc * 64 + csb * 16 + l15;
#pragma unroll
      for (int r = 0; r < 4; ++r) {
        int ig = rowBase + wr * 64 + rs * 16 + quad * 4 + r;
        float a = acc[rs][csb][r];
        bool same = (labc[csb] == labr[r]);
        float e = __expf(a * eN[r]);
        if (!same) {
          neg[r] += e;
        } else if (jl > ig) {
          pos[r] += a * SCALE;
          nlt[r] += 1.0f;
        }
      }
    }
#pragma unroll
    for (int r = 0; r < 4; ++r) {
      float n_ = neg[r], p_ = pos[r], c_ = nlt[r];
#pragma unroll
      for (int m = 1; m < 16; m <<= 1) {
        n_ += __shfl_xor(n_, m);
        p_ += __shfl_xor(p_, m);
        c_ += __shfl_xor(c_, m);
      }
      if (l15 == 0) {
        int row = wr * 64 + rs * 16 + quad * 4 + r;  // block-relative row
        redL[wc][0][row] = n_;
        redL[wc][1][row] = p_;
        redL[wc][2][row] = c_;
      }
    }
  }
  // Combine the two wc column-halves and store one partial per (cj,row).
  __syncthreads();
  if (tid < 128) {
    int o = cj * BS_TOT + b * NS + rowBase + tid;
    negP[o] = redL[0][0][tid] + redL[1][0][tid];
    posP[o] = redL[0][1][tid] + redL[1][1][tid];
    nltP[o] = redL[0][2][tid] + redL[1][2][tid];
  }
}

// ---------------- Kernel 4: combine partials -> loss ----------------
__global__ void final_kernel(const float* __restrict__ negP,
                             const float* __restrict__ posP,
                             const float* __restrict__ nltP,
                             const float* __restrict__ invGS,
                             const float* __restrict__ numneg,
                             float* __restrict__ out) {
  int idx = blockIdx.x * 256 + threadIdx.x;
  float neg = 0.0f, pos = 0.0f, nl = 0.0f;
#pragma unroll
  for (int c = 0; c < NCT; ++c) {
    neg += negP[c * BS_TOT + idx];
    pos += posP[c * BS_TOT + idx];
    nl += nltP[c * BS_TOT + idx];
  }
  float pa = 0.0f;
  if (numneg[idx] > 0.0f) pa = -(pos - nl * __logf(neg)) * invGS[idx];
#pragma unroll
  for (int m = 1; m < 64; m <<= 1) pa += __shfl_xor(pa, m);
  __shared__ float wsum[4];
  if ((threadIdx.x & 63) == 0) wsum[threadIdx.x >> 6] = pa;
  __syncthreads();
  if (threadIdx.x == 0) {
    float s = wsum[0] + wsum[1] + wsum[2] + wsum[3];
    atomicAdd(out, s * (1.0f / (float)NS));
  }
}

extern "C" void kernel_launch(void* const* d_in, const int* in_sizes, int n_in,
                              void* d_out, int out_size, void* d_ws,
                              size_t ws_size, hipStream_t stream) {
  (void)in_sizes;
  (void)n_in;
  (void)out_size;
  (void)ws_size;
  const float* feat = (const float*)d_in[0];
  const int* labels = (const int*)d_in[1];
  float* out = (float*)d_out;

  char* w = (char*)d_ws;
  unsigned short* featB = (unsigned short*)w;  // bf16 features, 50,331,648 B
  size_t off = (size_t)NB * NS * ND * 2;
  float* invN = (float*)(w + off);
  off += (size_t)BS_TOT * 4;
  float* invGS = (float*)(w + off);
  off += (size_t)BS_TOT * 4;
  float* numneg = (float*)(w + off);
  off += (size_t)BS_TOT * 4;
  int* labI = (int*)(w + off);
  off += (size_t)BS_TOT * 4;
  float* negP = (float*)(w + off);
  off += (size_t)NCT * BS_TOT * 4;
  float* posP = (float*)(w + off);
  off += (size_t)NCT * BS_TOT * 4;
  float* nltP = (float*)(w + off);
  off += (size_t)NCT * BS_TOT * 4;
  // total ws usage ~54 MB

  cvt_kernel<<<(NB * NS * ND) / (256 * 8), 256, 0, stream>>>(feat, featB);
  meta_kernel<<<NB, 256, 0, stream>>>(labels, invN, invGS, numneg, labI, out);
  gram_kernel<<<2048, 256, 0, stream>>>(featB, labI, invN, negP, posP, nltP);
  final_kernel<<<BS_TOT / 256, 256, 0, stream>>>(negP, posP, nltP, invGS,
                                                 numneg, out);
}

// Round 4
// 236.357 us; speedup vs baseline: 1.1525x; 1.1525x over previous
//
#include <hip/hip_runtime.h>
#include <hip/hip_bf16.h>

#define NB 32
#define NS 1024
#define ND 768
#define BS_TOT (NB * NS)  // 32768
#define NCT 8             // column tiles per row (one per block)

// sim scale = 1 / (0.7 * sqrt(768))
#define SCALE 0.05154913f

typedef __attribute__((ext_vector_type(8))) short bf16x8;  // 8 bf16 = 4 VGPRs
typedef __attribute__((ext_vector_type(4))) float f32x4;

__device__ __forceinline__ unsigned short f2bf(float f) {
  __hip_bfloat16 h = __float2bfloat16(f);
  return *reinterpret_cast<unsigned short*>(&h);
}

__device__ __forceinline__ void gload_lds16(const unsigned short* g, short* l) {
  __builtin_amdgcn_global_load_lds(
      (const __attribute__((address_space(1))) unsigned int*)g,
      (__attribute__((address_space(3))) unsigned int*)l,
      16 /*bytes*/, 0 /*offset*/, 0 /*aux*/);
}

// ---------------- Kernel 1: fp32 -> bf16 convert (8 elems/thread) ----------
__global__ void cvt_kernel(const float* __restrict__ in,
                           unsigned short* __restrict__ out) {
  int i = (blockIdx.x * 256 + threadIdx.x) * 8;
  float4 v0 = *reinterpret_cast<const float4*>(in + i);
  float4 v1 = *reinterpret_cast<const float4*>(in + i + 4);
  ushort4 o0, o1;
  o0.x = f2bf(v0.x); o0.y = f2bf(v0.y); o0.z = f2bf(v0.z); o0.w = f2bf(v0.w);
  o1.x = f2bf(v1.x); o1.y = f2bf(v1.y); o1.z = f2bf(v1.z); o1.w = f2bf(v1.w);
  *reinterpret_cast<ushort4*>(out + i) = o0;
  *reinterpret_cast<ushort4*>(out + i + 4) = o1;
}

// ---------------- Kernel 2: per-anchor metadata ----------------
// Handles labels arriving as either int32 or raw int64 (little-endian): if
// int64, every odd 32-bit word of the label buffer is the zero high-word.
__global__ void meta_kernel(const int* __restrict__ lr,
                            float* __restrict__ invN,
                            float* __restrict__ invGS,
                            float* __restrict__ numneg,
                            int* __restrict__ labI,
                            float* __restrict__ out) {
  __shared__ int cnt[16];
  __shared__ int is64;
  int b = blockIdx.x, t = threadIdx.x;
  if (t == 0) is64 = 1;
  if (t < 16) cnt[t] = 0;
  __syncthreads();
  int bad = 0;
  for (int k = t; k < 1024; k += 256) bad |= lr[2 * k + 1];
  if (bad) atomicAnd(&is64, 0);
  __syncthreads();
  const bool i64 = (is64 != 0);
  for (int i = t; i < NS; i += 256) {
    int gi = b * NS + i;
    int lab = (i64 ? lr[2 * gi] : lr[gi]) & 15;
    atomicAdd(&cnt[lab], 1);
  }
  __syncthreads();
  for (int i = t; i < NS; i += 256) {
    int gi = b * NS + i;
    int lab = (i64 ? lr[2 * gi] : lr[gi]) & 15;
    int gs = cnt[lab];
    int nn = NS - gs;
    invN[gi] = nn > 0 ? 1.0f / (float)nn : 0.0f;
    invGS[gi] = 1.0f / (float)gs;
    numneg[gi] = (float)nn;
    labI[gi] = lab;
  }
  if (b == 0 && t == 0) out[0] = 0.0f;  // d_out is poisoned before each launch
}

// ---------------- Kernel 3: fused Gram + SupCon epilogue ----------------
// ONE 128x128 sim tile per block. Grid 2048 = 32 batches x 8 row x 8 col
// tiles, decoded XCD-affine (xcd = bid&7 owns 4 batches -> ~6 MB working set
// per XCD for L2 locality; measured FETCH 271->108 MB in round 3).
// __launch_bounds__(256,3): combined VGPR+AGPR cap 170. Round 3's (256,4)
// capped at 128 = exactly the 64-AGPR accumulator + 64 arch VGPRs -> spilled
// (WRITE_SIZE 115 MB scratch, gram 121 us). Unconstrained uses 120 arch + 64
// acc = 184 -> only 2 blocks/CU. 170 = 3 blocks/CU with a mild, spill-free
// squeeze (needs 106 arch).
__global__ __launch_bounds__(256, 3) void gram_kernel(
    const unsigned short* __restrict__ featB, const int* __restrict__ labI,
    const float* __restrict__ invN, float* __restrict__ negP,
    float* __restrict__ posP, float* __restrict__ nltP) {
  const int bid = blockIdx.x;
  const int xcd = bid & 7;
  const int idx = bid >> 3;            // 0..255
  const int b = xcd * 4 + (idx & 3);   // 4 batches per XCD
  const int t2 = idx >> 2;             // 0..63
  const int rt = t2 & 7;
  const int cj = t2 >> 3;              // 0..7 column tile

  const int tid = threadIdx.x;
  const int lane = tid & 63;
  const int w = tid >> 6;
  const int wr = w >> 1, wc = w & 1;
  const int quad = lane >> 4, l15 = lane & 15;

  __shared__ alignas(16) short As[128 * 32];  // 8 KB, row-major [row][k]
  __shared__ alignas(16) short Bs[128 * 32];  // 8 KB, row-major [col][k]
  __shared__ float redL[2][3][128];           // [wc][neg/pos/nlt][row], 3 KB

  const int rowBase = rt * 128;
  const int colBase = cj * 128;
  const size_t featA = (size_t)(b * NS + rowBase) * ND;
  const size_t featBb = (size_t)(b * NS + colBase) * ND;

  f32x4 acc[4][4];
  const f32x4 zv = {0.0f, 0.0f, 0.0f, 0.0f};
#pragma unroll
  for (int rs = 0; rs < 4; ++rs)
#pragma unroll
    for (int csb = 0; csb < 4; ++csb) acc[rs][csb] = zv;

  for (int k0 = 0; k0 < ND; k0 += 32) {
    __syncthreads();  // previous iteration's ds_reads done before restage
#pragma unroll
    for (int rnd = 0; rnd < 2; ++rnd) {
      int s = rnd * 256 + tid;
      int row = s >> 2, ch = s & 3;
      gload_lds16(featB + featA + (size_t)row * ND + k0 + ch * 8, &As[s * 8]);
    }
#pragma unroll
    for (int rnd = 0; rnd < 2; ++rnd) {
      int s = rnd * 256 + tid;
      int row = s >> 2, ch = s & 3;
      gload_lds16(featB + featBb + (size_t)row * ND + k0 + ch * 8, &Bs[s * 8]);
    }
    __syncthreads();  // vmcnt drain: staging visible

    bf16x8 av[4], bv[4];
#pragma unroll
    for (int rs = 0; rs < 4; ++rs)
      av[rs] = *reinterpret_cast<const bf16x8*>(
          &As[(wr * 64 + rs * 16 + l15) * 32 + quad * 8]);
#pragma unroll
    for (int csb = 0; csb < 4; ++csb)
      bv[csb] = *reinterpret_cast<const bf16x8*>(
          &Bs[(wc * 64 + csb * 16 + l15) * 32 + quad * 8]);
#pragma unroll
    for (int rs = 0; rs < 4; ++rs)
#pragma unroll
      for (int csb = 0; csb < 4; ++csb)
        acc[rs][csb] = __builtin_amdgcn_mfma_f32_16x16x32_bf16(
            av[rs], bv[csb], acc[rs][csb], 0, 0, 0);
  }

  // ---- Epilogue (once per block). Column labels for this wave's 64 cols.
  int labc[4];
#pragma unroll
  for (int csb = 0; csb < 4; ++csb)
    labc[csb] = labI[b * NS + colBase + wc * 64 + csb * 16 + l15];

  // rs-by-rs to cap register pressure (acc still live while reducing).
#pragma unroll
  for (int rs = 0; rs < 4; ++rs) {
    int labr[4];
    float eN[4];
    const int ibase = b * NS + rowBase + wr * 64 + rs * 16 + quad * 4;
#pragma unroll
    for (int r = 0; r < 4; ++r) {
      labr[r] = labI[ibase + r];
      eN[r] = invN[ibase + r] * SCALE;
    }
    float neg[4] = {0, 0, 0, 0}, pos[4] = {0, 0, 0, 0}, nlt[4] = {0, 0, 0, 0};
#pragma unroll
    for (int csb = 0; csb < 4; ++csb) {
      int jl = colBase + wc * 64 + csb * 16 + l15;
#pragma unroll
      for (int r = 0; r < 4; ++r) {
        int ig = rowBase + wr * 64 + rs * 16 + quad * 4 + r;
        float a = acc[rs][csb][r];
        bool same = (labc[csb] == labr[r]);
        float e = __expf(a * eN[r]);
        if (!same) {
          neg[r] += e;
        } else if (jl > ig) {
          pos[r] += a * SCALE;
          nlt[r] += 1.0f;
        }
      }
    }
#pragma unroll
    for (int r = 0; r < 4; ++r) {
      float n_ = neg[r], p_ = pos[r], c_ = nlt[r];
#pragma unroll
      for (int m = 1; m < 16; m <<= 1) {
        n_ += __shfl_xor(n_, m);
        p_ += __shfl_xor(p_, m);
        c_ += __shfl_xor(c_, m);
      }
      if (l15 == 0) {
        int row = wr * 64 + rs * 16 + quad * 4 + r;  // block-relative row
        redL[wc][0][row] = n_;
        redL[wc][1][row] = p_;
        redL[wc][2][row] = c_;
      }
    }
  }
  // Combine the two wc column-halves and store one partial per (cj,row).
  __syncthreads();
  if (tid < 128) {
    int o = cj * BS_TOT + b * NS + rowBase + tid;
    negP[o] = redL[0][0][tid] + redL[1][0][tid];
    posP[o] = redL[0][1][tid] + redL[1][1][tid];
    nltP[o] = redL[0][2][tid] + redL[1][2][tid];
  }
}

// ---------------- Kernel 4: combine partials -> loss ----------------
__global__ void final_kernel(const float* __restrict__ negP,
                             const float* __restrict__ posP,
                             const float* __restrict__ nltP,
                             const float* __restrict__ invGS,
                             const float* __restrict__ numneg,
                             float* __restrict__ out) {
  int idx = blockIdx.x * 256 + threadIdx.x;
  float neg = 0.0f, pos = 0.0f, nl = 0.0f;
#pragma unroll
  for (int c = 0; c < NCT; ++c) {
    neg += negP[c * BS_TOT + idx];
    pos += posP[c * BS_TOT + idx];
    nl += nltP[c * BS_TOT + idx];
  }
  float pa = 0.0f;
  if (numneg[idx] > 0.0f) pa = -(pos - nl * __logf(neg)) * invGS[idx];
#pragma unroll
  for (int m = 1; m < 64; m <<= 1) pa += __shfl_xor(pa, m);
  __shared__ float wsum[4];
  if ((threadIdx.x & 63) == 0) wsum[threadIdx.x >> 6] = pa;
  __syncthreads();
  if (threadIdx.x == 0) {
    float s = wsum[0] + wsum[1] + wsum[2] + wsum[3];
    atomicAdd(out, s * (1.0f / (float)NS));
  }
}

extern "C" void kernel_launch(void* const* d_in, const int* in_sizes, int n_in,
                              void* d_out, int out_size, void* d_ws,
                              size_t ws_size, hipStream_t stream) {
  (void)in_sizes;
  (void)n_in;
  (void)out_size;
  (void)ws_size;
  const float* feat = (const float*)d_in[0];
  const int* labels = (const int*)d_in[1];
  float* out = (float*)d_out;

  char* w = (char*)d_ws;
  unsigned short* featB = (unsigned short*)w;  // bf16 features, 50,331,648 B
  size_t off = (size_t)NB * NS * ND * 2;
  float* invN = (float*)(w + off);
  off += (size_t)BS_TOT * 4;
  float* invGS = (float*)(w + off);
  off += (size_t)BS_TOT * 4;
  float* numneg = (float*)(w + off);
  off += (size_t)BS_TOT * 4;
  int* labI = (int*)(w + off);
  off += (size_t)BS_TOT * 4;
  float* negP = (float*)(w + off);
  off += (size_t)NCT * BS_TOT * 4;
  float* posP = (float*)(w + off);
  off += (size_t)NCT * BS_TOT * 4;
  float* nltP = (float*)(w + off);
  off += (size_t)NCT * BS_TOT * 4;
  // total ws usage ~54 MB

  cvt_kernel<<<(NB * NS * ND) / (256 * 8), 256, 0, stream>>>(feat, featB);
  meta_kernel<<<NB, 256, 0, stream>>>(labels, invN, invGS, numneg, labI, out);
  gram_kernel<<<2048, 256, 0, stream>>>(featB, labI, invN, negP, posP, nltP);
  final_kernel<<<BS_TOT / 256, 256, 0, stream>>>(negP, posP, nltP, invGS,
                                                 numneg, out);
}

// Round 6
// 205.373 us; speedup vs baseline: 1.3264x; 1.1509x over previous
//
#include <hip/hip_runtime.h>
#include <hip/hip_bf16.h>

#define NB 32
#define NS 1024
#define ND 768
#define BS_TOT (NB * NS)  // 32768
#define NCT 8             // partial-split slots per anchor
#define GRAM_GRID 1152    // 32 batches x 36 upper-triangle tiles. MUST match
                          // the decode below; blocks beyond 36 tiles would
                          // previously infinite-loop (round-5 hang).

// sim scale = 1 / (0.7 * sqrt(768))
#define SCALE 0.05154913f

typedef __attribute__((ext_vector_type(8))) short bf16x8;  // 8 bf16 = 4 VGPRs
typedef __attribute__((ext_vector_type(4))) float f32x4;

__device__ __forceinline__ unsigned short f2bf(float f) {
  __hip_bfloat16 h = __float2bfloat16(f);
  return *reinterpret_cast<unsigned short*>(&h);
}

__device__ __forceinline__ void gload_lds16(const unsigned short* g, short* l) {
  __builtin_amdgcn_global_load_lds(
      (const __attribute__((address_space(1))) unsigned int*)g,
      (__attribute__((address_space(3))) unsigned int*)l,
      16 /*bytes*/, 0 /*offset*/, 0 /*aux*/);
}

// ---------------- Kernel 1: fp32 -> bf16 convert (8 elems/thread) ----------
__global__ void cvt_kernel(const float* __restrict__ in,
                           unsigned short* __restrict__ out) {
  int i = (blockIdx.x * 256 + threadIdx.x) * 8;
  float4 v0 = *reinterpret_cast<const float4*>(in + i);
  float4 v1 = *reinterpret_cast<const float4*>(in + i + 4);
  ushort4 o0, o1;
  o0.x = f2bf(v0.x); o0.y = f2bf(v0.y); o0.z = f2bf(v0.z); o0.w = f2bf(v0.w);
  o1.x = f2bf(v1.x); o1.y = f2bf(v1.y); o1.z = f2bf(v1.z); o1.w = f2bf(v1.w);
  *reinterpret_cast<ushort4*>(out + i) = o0;
  *reinterpret_cast<ushort4*>(out + i + 4) = o1;
}

// ---------------- Kernel 2: per-anchor metadata ----------------
// Handles labels arriving as either int32 or raw int64 (little-endian): if
// int64, every odd 32-bit word of the label buffer is the zero high-word.
__global__ void meta_kernel(const int* __restrict__ lr,
                            float* __restrict__ invN,
                            float* __restrict__ invGS,
                            float* __restrict__ numneg,
                            int* __restrict__ labI,
                            float* __restrict__ out) {
  __shared__ int cnt[16];
  __shared__ int is64;
  int b = blockIdx.x, t = threadIdx.x;
  if (t == 0) is64 = 1;
  if (t < 16) cnt[t] = 0;
  __syncthreads();
  int bad = 0;
  for (int k = t; k < 1024; k += 256) bad |= lr[2 * k + 1];
  if (bad) atomicAnd(&is64, 0);
  __syncthreads();
  const bool i64 = (is64 != 0);
  for (int i = t; i < NS; i += 256) {
    int gi = b * NS + i;
    int lab = (i64 ? lr[2 * gi] : lr[gi]) & 15;
    atomicAdd(&cnt[lab], 1);
  }
  __syncthreads();
  for (int i = t; i < NS; i += 256) {
    int gi = b * NS + i;
    int lab = (i64 ? lr[2 * gi] : lr[gi]) & 15;
    int gs = cnt[lab];
    int nn = NS - gs;
    invN[gi] = nn > 0 ? 1.0f / (float)nn : 0.0f;
    invGS[gi] = 1.0f / (float)gs;
    numneg[gi] = (float)nn;
    labI[gi] = lab;
  }
  if (b == 0 && t == 0) out[0] = 0.0f;  // d_out is poisoned before each launch
}

// ---------------- Kernel 3: symmetric Gram + SupCon epilogue ----------------
// sim is symmetric -> only tiles rt<=cj (36/batch instead of 64, -44% work).
// Off-diagonal tile (rt<cj): row-anchors i get neg (diff label) + pos/nlt
// (same label, j>i always since cj>rt); col-anchors j get neg only (i<j is
// never a counted positive). Partial-split bookkeeping (race-free, no
// atomics): row partials stored at split cj (covers splits t..7 for anchor
// with tile coord t), col partials at split rt (covers 0..t-1) -> each
// (split, anchor) written by exactly one block; final_kernel sums all 8.
// BK=64 (12 barrier-drains instead of 24) + XOR chunk swizzle: LDS row chunk
// ch holds global chunk ch^(row&7) -- staging keeps the wave-uniform-base +
// lane*16 contract (only global addrs are permuted), and ds_read_b128
// fragments spread across all 32 banks (2-way = free) instead of 8/16-way.
__global__ __launch_bounds__(256, 3) void gram_kernel(
    const unsigned short* __restrict__ featB, const int* __restrict__ labI,
    const float* __restrict__ invN, float* __restrict__ negP,
    float* __restrict__ posP, float* __restrict__ nltP) {
  const int bid = blockIdx.x;
  const int xcd = bid & 7;
  const int idx = bid >> 3;           // 0..143
  const int b = xcd * 4 + (idx & 3);  // 4 batches per XCD (L2 locality)
  int rem = idx >> 2;                 // 0..35 upper-triangle tile id
  int rt = 0;
  while (rt < 7 && rem >= 8 - rt) { rem -= 8 - rt; ++rt; }  // bounded decode
  const int cj = rt + rem;
  const bool diag = (rt == cj);

  const int tid = threadIdx.x;
  const int lane = tid & 63;
  const int w = tid >> 6;
  const int wr = w >> 1, wc = w & 1;
  const int quad = lane >> 4, l15 = lane & 15;

  __shared__ alignas(16) short smem[2 * 128 * 64];  // A tile | B tile, 32 KB
  __shared__ float redL[2][3][128];                 // [wc][neg/pos/nlt][row]
  __shared__ float colRed[2][128];                  // [wr][col] col-neg

  const int rowBase = rt * 128;
  const int colBase = cj * 128;
  const size_t featA = (size_t)(b * NS + rowBase) * ND;
  const size_t featBb = (size_t)(b * NS + colBase) * ND;
  const int bOff = diag ? 0 : 8192;  // bv reads from A region on diagonal

  f32x4 acc[4][4];
  const f32x4 zv = {0.0f, 0.0f, 0.0f, 0.0f};
#pragma unroll
  for (int rs = 0; rs < 4; ++rs)
#pragma unroll
    for (int csb = 0; csb < 4; ++csb) acc[rs][csb] = zv;

  for (int k0 = 0; k0 < ND; k0 += 64) {
    __syncthreads();  // previous iteration's ds_reads done before restage
    // Stage A (and B unless diagonal): 128 rows x 64 elems, 16 B chunks,
    // chunk position ch holds global chunk ch^(row&7).
#pragma unroll
    for (int rnd = 0; rnd < 4; ++rnd) {
      int s = rnd * 256 + tid;           // 0..1023
      int row = s >> 3, ch = s & 7;
      int gch = ch ^ (row & 7);
      gload_lds16(featB + featA + (size_t)row * ND + k0 + gch * 8,
                  &smem[s * 8]);
    }
    if (!diag) {
#pragma unroll
      for (int rnd = 0; rnd < 4; ++rnd) {
        int s = rnd * 256 + tid;
        int row = s >> 3, ch = s & 7;
        int gch = ch ^ (row & 7);
        gload_lds16(featB + featBb + (size_t)row * ND + k0 + gch * 8,
                    &smem[8192 + s * 8]);
      }
    }
    __syncthreads();  // vmcnt drain: staging visible

#pragma unroll
    for (int ks = 0; ks < 2; ++ks) {
      bf16x8 av[4], bv[4];
#pragma unroll
      for (int rs = 0; rs < 4; ++rs) {
        int row = wr * 64 + rs * 16 + l15;
        int p = (ks * 4 + quad) ^ (row & 7);
        av[rs] = *reinterpret_cast<const bf16x8*>(&smem[row * 64 + p * 8]);
      }
#pragma unroll
      for (int csb = 0; csb < 4; ++csb) {
        int col = wc * 64 + csb * 16 + l15;
        int p = (ks * 4 + quad) ^ (col & 7);
        bv[csb] =
            *reinterpret_cast<const bf16x8*>(&smem[bOff + col * 64 + p * 8]);
      }
#pragma unroll
      for (int rs = 0; rs < 4; ++rs)
#pragma unroll
        for (int csb = 0; csb < 4; ++csb)
          acc[rs][csb] = __builtin_amdgcn_mfma_f32_16x16x32_bf16(
              av[rs], bv[csb], acc[rs][csb], 0, 0, 0);
    }
  }

  // ---- Epilogue. Column labels + invN for this wave's 64 columns.
  int labc[4];
  float eNc[4];
#pragma unroll
  for (int csb = 0; csb < 4; ++csb) {
    int j = b * NS + colBase + wc * 64 + csb * 16 + l15;
    labc[csb] = labI[j];
    eNc[csb] = invN[j] * SCALE;
  }
  float negc[4] = {0, 0, 0, 0};  // col-anchor neg partial (off-diag only)

#pragma unroll
  for (int rs = 0; rs < 4; ++rs) {
    int labr[4];
    float eN[4];
    const int ibase = b * NS + rowBase + wr * 64 + rs * 16 + quad * 4;
#pragma unroll
    for (int r = 0; r < 4; ++r) {
      labr[r] = labI[ibase + r];
      eN[r] = invN[ibase + r] * SCALE;
    }
    float neg[4] = {0, 0, 0, 0}, pos[4] = {0, 0, 0, 0}, nlt[4] = {0, 0, 0, 0};
#pragma unroll
    for (int csb = 0; csb < 4; ++csb) {
      int jl = colBase + wc * 64 + csb * 16 + l15;
#pragma unroll
      for (int r = 0; r < 4; ++r) {
        int ig = rowBase + wr * 64 + rs * 16 + quad * 4 + r;
        float a = acc[rs][csb][r];
        bool same = (labc[csb] == labr[r]);
        float e = __expf(a * eN[r]);
        if (!same) {
          neg[r] += e;
        } else if (jl > ig) {
          pos[r] += a * SCALE;
          nlt[r] += 1.0f;
        }
        if (!diag && !same) negc[csb] += __expf(a * eNc[csb]);
      }
    }
#pragma unroll
    for (int r = 0; r < 4; ++r) {
      float n_ = neg[r], p_ = pos[r], c_ = nlt[r];
#pragma unroll
      for (int m = 1; m < 16; m <<= 1) {
        n_ += __shfl_xor(n_, m);
        p_ += __shfl_xor(p_, m);
        c_ += __shfl_xor(c_, m);
      }
      if (l15 == 0) {
        int row = wr * 64 + rs * 16 + quad * 4 + r;  // block-relative row
        redL[wc][0][row] = n_;
        redL[wc][1][row] = p_;
        redL[wc][2][row] = c_;
      }
    }
  }
  // Col-anchor reduction over rows: quads hold disjoint row quartets.
  if (!diag) {
#pragma unroll
    for (int csb = 0; csb < 4; ++csb) {
      float nc = negc[csb];
      nc += __shfl_xor(nc, 16);
      nc += __shfl_xor(nc, 32);
      if (quad == 0) colRed[wr][wc * 64 + csb * 16 + l15] = nc;
    }
  }
  __syncthreads();
  // Row partials -> split cj.
  if (tid < 128) {
    int o = cj * BS_TOT + b * NS + rowBase + tid;
    negP[o] = redL[0][0][tid] + redL[1][0][tid];
    posP[o] = redL[0][1][tid] + redL[1][1][tid];
    nltP[o] = redL[0][2][tid] + redL[1][2][tid];
  }
  // Col partials -> split rt (off-diagonal only; neg only).
  if (!diag && tid < 128) {
    int o = rt * BS_TOT + b * NS + colBase + tid;
    negP[o] = colRed[0][tid] + colRed[1][tid];
    posP[o] = 0.0f;
    nltP[o] = 0.0f;
  }
}

// ---------------- Kernel 4: combine partials -> loss ----------------
__global__ void final_kernel(const float* __restrict__ negP,
                             const float* __restrict__ posP,
                             const float* __restrict__ nltP,
                             const float* __restrict__ invGS,
                             const float* __restrict__ numneg,
                             float* __restrict__ out) {
  int idx = blockIdx.x * 256 + threadIdx.x;
  float neg = 0.0f, pos = 0.0f, nl = 0.0f;
#pragma unroll
  for (int c = 0; c < NCT; ++c) {
    neg += negP[c * BS_TOT + idx];
    pos += posP[c * BS_TOT + idx];
    nl += nltP[c * BS_TOT + idx];
  }
  float pa = 0.0f;
  if (numneg[idx] > 0.0f) pa = -(pos - nl * __logf(neg)) * invGS[idx];
#pragma unroll
  for (int m = 1; m < 64; m <<= 1) pa += __shfl_xor(pa, m);
  __shared__ float wsum[4];
  if ((threadIdx.x & 63) == 0) wsum[threadIdx.x >> 6] = pa;
  __syncthreads();
  if (threadIdx.x == 0) {
    float s = wsum[0] + wsum[1] + wsum[2] + wsum[3];
    atomicAdd(out, s * (1.0f / (float)NS));
  }
}

extern "C" void kernel_launch(void* const* d_in, const int* in_sizes, int n_in,
                              void* d_out, int out_size, void* d_ws,
                              size_t ws_size, hipStream_t stream) {
  (void)in_sizes;
  (void)n_in;
  (void)out_size;
  (void)ws_size;
  const float* feat = (const float*)d_in[0];
  const int* labels = (const int*)d_in[1];
  float* out = (float*)d_out;

  char* w = (char*)d_ws;
  unsigned short* featB = (unsigned short*)w;  // bf16 features, 50,331,648 B
  size_t off = (size_t)NB * NS * ND * 2;
  float* invN = (float*)(w + off);
  off += (size_t)BS_TOT * 4;
  float* invGS = (float*)(w + off);
  off += (size_t)BS_TOT * 4;
  float* numneg = (float*)(w + off);
  off += (size_t)BS_TOT * 4;
  int* labI = (int*)(w + off);
  off += (size_t)BS_TOT * 4;
  float* negP = (float*)(w + off);
  off += (size_t)NCT * BS_TOT * 4;
  float* posP = (float*)(w + off);
  off += (size_t)NCT * BS_TOT * 4;
  float* nltP = (float*)(w + off);
  off += (size_t)NCT * BS_TOT * 4;
  // total ws usage ~54 MB

  cvt_kernel<<<(NB * NS * ND) / (256 * 8), 256, 0, stream>>>(feat, featB);
  meta_kernel<<<NB, 256, 0, stream>>>(labels, invN, invGS, numneg, labI, out);
  gram_kernel<<<GRAM_GRID, 256, 0, stream>>>(featB, labI, invN, negP, posP,
                                             nltP);
  final_kernel<<<BS_TOT / 256, 256, 0, stream>>>(negP, posP, nltP, invGS,
                                                 numneg, out);
}